// Round 8
// baseline (648.873 us; speedup 1.0000x reference)
//
#include <hip/hip_runtime.h>
#include <hip/hip_bf16.h>
#include <math.h>

// Hyperbolic (Poincare-ball) pairwise distance:
//   out[b,h,n,m] = arccosh(1 + 2*c*||q_n-k_m||^2 / ((1-c||q_n||^2)(1-c||k_m||^2)))
// c = 1.0. Shapes: q,k f32[4,8,2048,64] -> out f32[4,8,2048,2048].
//
// R1 -> R3: VALU fixes. 424 -> 160 us.  R4/R5: occupancy+/plain stores regress.
// R6: LDS-bounced epilogue, full-line 1024 B stores. 160 -> 115.5 us.
// R7: lgkm-only barriers: NO change -> store drain was never serializing.
// R8: DRAM burst locality. At 115 us we run 5.3 TB/s combined vs 6.5+ TB/s
//   memset on same chip. 128x128 tiles store 512 B segments at 8 KB stride
//   (DRAM page thrash). Restructure: block = 16 full rows x 2048 cols ->
//   output region is 128 KB CONTIGUOUS; waves stream whole 8 KB rows.
//   K (512 KB/bh) chunked 256-rows-at-a-time through LDS; results live in
//   128 persistent VGPRs (statically indexed, chunk loop fully unrolled).
//   XCD-grouped mapping (bid&7=XCD, 4 bh per XCD) keeps each bh's k-panel
//   resident in its XCD's 4 MB L2 across the 128 blocks that re-read it.

typedef __bf16 bf16x8 __attribute__((ext_vector_type(8)));
typedef float f32x4 __attribute__((ext_vector_type(4)));
typedef unsigned short u16x8 __attribute__((ext_vector_type(8)));

#define NSEQ 2048
#define DDIM 64
#define QROWS 16       // q-rows per block (row slab)
#define KCH 256        // k-rows staged per chunk
#define NCH 8          // 2048 / KCH
#define LDSW 72        // ushort stride of Ks rows (144 B)
#define LOUTW 2052     // f32 stride of Lout rows (2048 + 4 pad)

// Barrier that does NOT drain vmcnt (nt stores keep flying); LDS-hazard only.
#define LGKM_BARRIER()                                        \
    do {                                                      \
        asm volatile("s_waitcnt lgkmcnt(0)" ::: "memory");    \
        __builtin_amdgcn_s_barrier();                         \
    } while (0)

static __device__ __forceinline__ unsigned short f32_to_bf16_rne(float f) {
    unsigned int u = __builtin_bit_cast(unsigned int, f);
    u += 0x7fffu + ((u >> 16) & 1u);   // round-to-nearest-even
    return (unsigned short)(u >> 16);
}

__global__ __launch_bounds__(256, 2)
void hyp_dist_rowslab_kernel(const float* __restrict__ qg,
                             const float* __restrict__ kg,
                             float* __restrict__ outg)
{
    __shared__ __align__(16) unsigned short Ks[KCH * LDSW];  // 36864 B
    __shared__ __align__(16) float kn_ch[KCH];               // ||k||^2
    __shared__ __align__(16) float ki_ch[KCH];               // 1/(1-||k||^2)
    __shared__ __align__(16) float Lout[4 * LOUTW];          // 32832 B bounce

    // XCD-aware mapping: dispatch round-robins blocks over 8 XCDs (bid&7).
    // Give each XCD a contiguous run of 4 bh's -> k/q panels L2-resident.
    const int bid = blockIdx.x;
    const int xcd = bid & 7;
    const int ii  = bid >> 3;                 // 0..511
    const int bh  = (xcd << 2) | (ii >> 7);   // 0..31
    const int rg  = ii & 127;                 // row-group within bh

    const int t    = threadIdx.x;   // 256 threads = 4 waves
    const int wid  = t >> 6;
    const int lane = t & 63;
    const int lr   = lane & 15;
    const int lg   = (lane >> 4) & 3;

    // ---- Q fragments direct from global (bf16) + exact f32 row norm ----
    // Lane (lr, lg) holds q[row=lr] dims {ks*32 + lg*8 .. +8} for ks=0,1.
    const float* qrow = qg + ((size_t)bh * NSEQ + (size_t)(rg * QROWS + lr)) * DDIM;
    bf16x8 af[2];
    float qnorm = 0.f;
    #pragma unroll
    for (int ks = 0; ks < 2; ++ks) {
        float4 v0 = *reinterpret_cast<const float4*>(qrow + ks * 32 + lg * 8);
        float4 v1 = *reinterpret_cast<const float4*>(qrow + ks * 32 + lg * 8 + 4);
        qnorm += v0.x*v0.x + v0.y*v0.y + v0.z*v0.z + v0.w*v0.w
               + v1.x*v1.x + v1.y*v1.y + v1.z*v1.z + v1.w*v1.w;
        u16x8 b;
        b[0] = f32_to_bf16_rne(v0.x); b[1] = f32_to_bf16_rne(v0.y);
        b[2] = f32_to_bf16_rne(v0.z); b[3] = f32_to_bf16_rne(v0.w);
        b[4] = f32_to_bf16_rne(v1.x); b[5] = f32_to_bf16_rne(v1.y);
        b[6] = f32_to_bf16_rne(v1.z); b[7] = f32_to_bf16_rne(v1.w);
        af[ks] = __builtin_bit_cast(bf16x8, b);
    }
    // lanes {lr, lr+16, lr+32, lr+48} cover all 64 dims of row lr
    qnorm += __shfl_xor(qnorm, 16);
    qnorm += __shfl_xor(qnorm, 32);
    const float qv = qnorm;
    const float q2 = 2.f * __builtin_amdgcn_rcpf(fmaxf(1.f - qnorm, 1e-3f));

    // ---- K chunk loop: stage -> MFMA -> fused epilogue into res[][] ----
    f32x4 res[NCH][4];   // 128 persistent floats; ALL indices static (unrolled)
    const float* kpan = kg + (size_t)bh * NSEQ * DDIM;

    #pragma unroll
    for (int ch = 0; ch < NCH; ++ch) {
        // protect Ks/kn_ch reuse: previous chunk's ds_reads must be done.
        LGKM_BARRIER();

        // stage 256 k-rows (64 KB f32 -> 36 KB bf16 LDS), fully coalesced:
        // iter it: thread t handles linear quad (it*256+t): row it*16+(t>>4),
        // dim-quad (t&15). 16-lane shfl tree -> exact f32 row norm.
        #pragma unroll
        for (int it = 0; it < 16; ++it) {
            const int row = it * 16 + (t >> 4);
            const int q4  = (t & 15) * 4;
            float4 v = *reinterpret_cast<const float4*>(
                kpan + (size_t)(ch * KCH + row) * DDIM + q4);
            float p = v.x*v.x + v.y*v.y + v.z*v.z + v.w*v.w;
            p += __shfl_xor(p, 1);
            p += __shfl_xor(p, 2);
            p += __shfl_xor(p, 4);
            p += __shfl_xor(p, 8);
            ushort4 b;
            b.x = f32_to_bf16_rne(v.x); b.y = f32_to_bf16_rne(v.y);
            b.z = f32_to_bf16_rne(v.z); b.w = f32_to_bf16_rne(v.w);
            *reinterpret_cast<ushort4*>(&Ks[row * LDSW + q4]) = b;
            if ((t & 15) == 0) {
                kn_ch[row] = p;
                ki_ch[row] = __builtin_amdgcn_rcpf(fmaxf(1.f - p, 1e-3f));
            }
        }
        LGKM_BARRIER();   // staging + norms visible

        // MFMA: wave w covers chunk cols [w*64, w*64+64).
        f32x4 acc[4];
        #pragma unroll
        for (int j = 0; j < 4; ++j) acc[j] = (f32x4){0.f, 0.f, 0.f, 0.f};
        #pragma unroll
        for (int ks = 0; ks < 2; ++ks) {
            #pragma unroll
            for (int j = 0; j < 4; ++j) {
                bf16x8 bj = *reinterpret_cast<const bf16x8*>(
                    &Ks[(wid * 64 + j * 16 + lr) * LDSW + ks * 32 + lg * 8]);
                acc[j] = __builtin_amdgcn_mfma_f32_16x16x32_bf16(
                             bj, af[ks], acc[j], 0, 0, 0);
            }
        }

        // fused epilogue: D layout q_idx = lane&15 (= lr), k_idx = lg*4 + r.
        #pragma unroll
        for (int j = 0; j < 4; ++j) {
            const int kb = wid * 64 + j * 16 + lg * 4;
            const f32x4 kv  = *reinterpret_cast<const f32x4*>(&kn_ch[kb]);
            const f32x4 kiv = *reinterpret_cast<const f32x4*>(&ki_ch[kb]);
            f32x4 r;
            #pragma unroll
            for (int e = 0; e < 4; ++e) {
                const float dot  = acc[j][e];
                const float diff = fmaxf(fmaf(-2.f, dot, qv + kv[e]), 0.f);
                const float tt   = diff * (q2 * kiv[e]);        // cosh_arg-1
                const float p    = fmaf(tt, tt, 2.f * tt);      // tt(tt+2)
                const float sq   = __builtin_amdgcn_sqrtf(p);
                const float x    = (1.f + tt) + sq;             // >= 1
                r[e] = __builtin_amdgcn_logf(x) * 0.69314718055994531f;
            }
            res[ch][j] = r;
        }
    }

    // ---- store: bounce 4 rows at a time through LDS; each wave then
    //      streams ONE full 8 KB output row as 8 contiguous 1 KB nt stores.
    const size_t orow0 = (size_t)bh * NSEQ + (size_t)rg * QROWS;
    #pragma unroll
    for (int g = 0; g < 4; ++g) {
        LGKM_BARRIER();   // Lout reuse: previous stream's ds_reads done
        if ((lr >> 2) == g) {
            #pragma unroll
            for (int ch = 0; ch < NCH; ++ch) {
                #pragma unroll
                for (int j = 0; j < 4; ++j) {
                    const int col = ch * 256 + wid * 64 + j * 16 + lg * 4;
                    *reinterpret_cast<f32x4*>(&Lout[(lr & 3) * LOUTW + col]) =
                        res[ch][j];
                }
            }
        }
        LGKM_BARRIER();   // Lout rows complete

        float* gp = outg + (orow0 + (size_t)(g * 4 + wid)) * NSEQ;
        #pragma unroll
        for (int m = 0; m < 8; ++m) {
            const f32x4 v = *reinterpret_cast<const f32x4*>(
                &Lout[wid * LOUTW + m * 256 + lane * 4]);
            __builtin_nontemporal_store(
                v, reinterpret_cast<f32x4*>(gp + m * 256 + lane * 4));
        }
    }
}

extern "C" void kernel_launch(void* const* d_in, const int* in_sizes, int n_in,
                              void* d_out, int out_size, void* d_ws, size_t ws_size,
                              hipStream_t stream) {
    const float* q = (const float*)d_in[0];
    const float* k = (const float*)d_in[1];
    float* out = (float*)d_out;
    // 32 (b,h) * 128 row-slabs of 16 rows x 2048 cols
    hyp_dist_rowslab_kernel<<<dim3(32 * 128), dim3(256), 0, stream>>>(q, k, out);
}

// Round 9
// 114.722 us; speedup vs baseline: 5.6561x; 5.6561x over previous
//
#include <hip/hip_runtime.h>
#include <hip/hip_bf16.h>
#include <math.h>

// Hyperbolic (Poincare-ball) pairwise distance:
//   out[b,h,n,m] = arccosh(1 + 2*c*||q_n-k_m||^2 / ((1-c||q_n||^2)(1-c||k_m||^2)))
// c = 1.0. Shapes: q,k f32[4,8,2048,64] -> out f32[4,8,2048,2048].
//
// R1 -> R3: VALU fixes. 424 -> 160 us.  R4/R5: occupancy+/plain stores regress.
// R6: LDS-bounced epilogue, full-line 1024 B/instr streaming stores. -> 115.5.
// R7: lgkm-only barriers: neutral (store drain already hidden). 115.4.
// R8: 16x2048 row-slab REGRESSED (649 us): 128 persistent result VGPRs
//   spilled to scratch (WRITE_SIZE 2.2x output) + L2 thrash. Reverted.
// R9: R6/R7 structure + XCD-grouped block mapping. Default dispatch spreads
//   each bh's tiles over all 8 XCDs -> every XCD touches all 32 MB of
//   panels (L2 = 4 MB/XCD), FETCH 74 MB vs 17 ideal. Now: xcd = bid&7 (HW
//   round-robin), each XCD owns 4 bh's; tc-fastest ordering makes the ~64
//   concurrent blocks per XCD write adjacent row-stripes (contiguous ~MB
//   regions at the memory controller) and keeps the active bh's Q+K panels
//   (1 MB) L2-resident.

typedef __bf16 bf16x8 __attribute__((ext_vector_type(8)));
typedef float f32x4 __attribute__((ext_vector_type(4)));

#define NSEQ 2048
#define DDIM 64
#define TILE 128
#define LDSW 72    // ushorts; 144 B row stride
#define LOUTW 132  // f32; 528 B row stride -> 2-way LDS conflicts (free)

// Barrier that does NOT drain vmcnt (nt stores keep flying); LDS-hazard only.
#define LGKM_BARRIER()                                        \
    do {                                                      \
        asm volatile("s_waitcnt lgkmcnt(0)" ::: "memory");    \
        __builtin_amdgcn_s_barrier();                         \
    } while (0)

static __device__ __forceinline__ unsigned short f32_to_bf16_rne(float f) {
    unsigned int u = __builtin_bit_cast(unsigned int, f);
    u += 0x7fffu + ((u >> 16) & 1u);   // round-to-nearest-even
    return (unsigned short)(u >> 16);
}

__global__ __launch_bounds__(256, 2)
void hyp_dist_tile_kernel(const float* __restrict__ qg,
                          const float* __restrict__ kg,
                          float* __restrict__ outg)
{
    // Qs+Ks (36864 B) aliased with Lout (64*132*4 = 33792 B): MFMA is done
    // with Qs/Ks before the first Lout write (barrier-protected).
    __shared__ __align__(16) unsigned char lds_raw[2 * TILE * LDSW * 2];
    __shared__ __align__(16) float qn[TILE];   // ||q||^2
    __shared__ __align__(16) float kn[TILE];   // ||k||^2
    __shared__ __align__(16) float qi2[TILE];  // 2/(1-||q||^2)
    __shared__ __align__(16) float ki[TILE];   // 1/(1-||k||^2)

    unsigned short* Qs = reinterpret_cast<unsigned short*>(lds_raw);
    unsigned short* Ks = Qs + TILE * LDSW;
    float*          Lout = reinterpret_cast<float*>(lds_raw);

    // XCD-grouped mapping (8192 % 8 == 0 -> bijective): xcd = bid&7 matches
    // the HW's round-robin dispatch; each XCD owns bh in [xcd*4, xcd*4+4);
    // tc varies fastest so concurrently-resident blocks form row-stripes.
    const int bid = blockIdx.x;
    const int xcd = bid & 7;
    const int ii  = bid >> 3;                 // 0..1023
    const int bh  = (xcd << 2) | (ii >> 8);   // 0..31
    const int rem = ii & 255;
    const int tr  = rem >> 4;
    const int tc  = rem & 15;

    const int t    = threadIdx.x;  // 256 threads = 4 waves
    const int row  = t >> 1;       // 0..127
    const int half = t & 1;        // each thread: half a row (32 f32)

    // ---- stage Q tile (f32 -> bf16 LDS) + row norms / recips in f32 ----
    {
        const float* src = qg + (((size_t)bh * NSEQ) + (size_t)(tr * TILE + row)) * DDIM
                              + half * 32;
        float partial = 0.f;
        #pragma unroll
        for (int i = 0; i < 8; ++i) {
            float4 v = reinterpret_cast<const float4*>(src)[i];
            partial += v.x * v.x + v.y * v.y + v.z * v.z + v.w * v.w;
            ushort4 b;
            b.x = f32_to_bf16_rne(v.x);
            b.y = f32_to_bf16_rne(v.y);
            b.z = f32_to_bf16_rne(v.z);
            b.w = f32_to_bf16_rne(v.w);
            *reinterpret_cast<ushort4*>(&Qs[row * LDSW + half * 32 + i * 4]) = b;
        }
        partial += __shfl_xor(partial, 1);
        if (half == 0) {
            qn[row]  = partial;
            // per-factor clamp 1e-3 -> product >= 1e-6 (reference clamp level)
            qi2[row] = 2.f * __builtin_amdgcn_rcpf(fmaxf(1.f - partial, 1e-3f));
        }
    }
    // ---- stage K tile ----
    {
        const float* src = kg + (((size_t)bh * NSEQ) + (size_t)(tc * TILE + row)) * DDIM
                              + half * 32;
        float partial = 0.f;
        #pragma unroll
        for (int i = 0; i < 8; ++i) {
            float4 v = reinterpret_cast<const float4*>(src)[i];
            partial += v.x * v.x + v.y * v.y + v.z * v.z + v.w * v.w;
            ushort4 b;
            b.x = f32_to_bf16_rne(v.x);
            b.y = f32_to_bf16_rne(v.y);
            b.z = f32_to_bf16_rne(v.z);
            b.w = f32_to_bf16_rne(v.w);
            *reinterpret_cast<ushort4*>(&Ks[row * LDSW + half * 32 + i * 4]) = b;
        }
        partial += __shfl_xor(partial, 1);
        if (half == 0) {
            kn[row] = partial;
            ki[row] = __builtin_amdgcn_rcpf(fmaxf(1.f - partial, 1e-3f));
        }
    }

    __syncthreads();

    // ---- MFMA: wave w owns rows {w*16..w*16+15} and {64+w*16..}, all 128 cols
    const int wid   = t >> 6;
    const int lane  = t & 63;
    const int lr    = lane & 15;
    const int lg    = lane >> 4;

    f32x4 acc[2][8];
    #pragma unroll
    for (int c = 0; c < 2; ++c)
        #pragma unroll
        for (int j = 0; j < 8; ++j)
            acc[c][j] = (f32x4){0.f, 0.f, 0.f, 0.f};

    // acc[c][j] = mfma(K_frag[j], Q_frag[c]): D layout q_idx = lane&15,
    // k_idx = (lane>>4)*4 + reg -> 4 regs = 4 consecutive output columns.
    #pragma unroll
    for (int ks = 0; ks < 2; ++ks) {
        bf16x8 af[2], bfr[8];
        #pragma unroll
        for (int c = 0; c < 2; ++c)
            af[c] = *reinterpret_cast<const bf16x8*>(
                        &Qs[(c * 64 + wid * 16 + lr) * LDSW + ks * 32 + lg * 8]);
        #pragma unroll
        for (int j = 0; j < 8; ++j)
            bfr[j] = *reinterpret_cast<const bf16x8*>(
                        &Ks[(j * 16 + lr) * LDSW + ks * 32 + lg * 8]);
        #pragma unroll
        for (int c = 0; c < 2; ++c)
            #pragma unroll
            for (int j = 0; j < 8; ++j)
                acc[c][j] = __builtin_amdgcn_mfma_f32_16x16x32_bf16(
                                bfr[j], af[c], acc[c][j], 0, 0, 0);
    }

    // ---- epilogue: two 64-row chunks bounced through LDS for full-line
    //      contiguous streaming stores (2 rows x 512 B per wave instr). ----
    const size_t out_bh = (size_t)bh * NSEQ * NSEQ;
    const int    l5  = lane >> 5;      // 0..1
    const int    c32 = lane & 31;      // 0..31

    #pragma unroll
    for (int c = 0; c < 2; ++c) {
        // c==0: all MFMA ds_reads done before overwriting Qs/Ks with Lout.
        // c==1: all chunk-0 streaming ds_reads done before overwriting Lout.
        // LDS-only hazard -> lgkm barrier; nt stores stay in flight.
        LGKM_BARRIER();

        const int   trow = c * 64 + wid * 16 + lr;   // row within 128-tile
        const float qv   = qn[trow];
        const float q2   = qi2[trow];                // 2/(1-|q|^2)
        #pragma unroll
        for (int j = 0; j < 8; ++j) {
            const int kb = j * 16 + lg * 4;
            const f32x4 kv  = *reinterpret_cast<const f32x4*>(&kn[kb]);
            const f32x4 kiv = *reinterpret_cast<const f32x4*>(&ki[kb]);
            f32x4 res;
            #pragma unroll
            for (int r = 0; r < 4; ++r) {
                const float dot  = acc[c][j][r];
                const float diff = fmaxf(fmaf(-2.f, dot, qv + kv[r]), 0.f); // ||q-k||^2
                const float tt   = diff * (q2 * kiv[r]);                    // cosh_arg-1
                const float p    = fmaf(tt, tt, 2.f * tt);                  // tt(tt+2)
                const float sq   = __builtin_amdgcn_sqrtf(p);
                const float x    = (1.f + tt) + sq;                         // >= 1
                const float l2   = __builtin_amdgcn_logf(x);                // log2
                res[r] = l2 * 0.69314718055994531f;                         // -> ln
            }
            *reinterpret_cast<f32x4*>(&Lout[(wid * 16 + lr) * LOUTW + kb]) = res;
        }

        // all ds_writes of this chunk visible before any wave streams it.
        LGKM_BARRIER();

        // stream chunk: wave w -> chunk rows w*16..w*16+15; per instr 2 full rows.
        #pragma unroll
        for (int m = 0; m < 8; ++m) {
            const int crow = wid * 16 + m * 2 + l5;
            const f32x4 v  = *reinterpret_cast<const f32x4*>(&Lout[crow * LOUTW + c32 * 4]);
            float* gp = outg + out_bh
                      + (size_t)(tr * TILE + c * 64 + crow) * NSEQ
                      + (size_t)(tc * TILE + c32 * 4);
            __builtin_nontemporal_store(v, reinterpret_cast<f32x4*>(gp));
        }
    }
}

extern "C" void kernel_launch(void* const* d_in, const int* in_sizes, int n_in,
                              void* d_out, int out_size, void* d_ws, size_t ws_size,
                              hipStream_t stream) {
    const float* q = (const float*)d_in[0];
    const float* k = (const float*)d_in[1];
    float* out = (float*)d_out;
    // 32 (b,h) * 16 * 16 tiles of 128x128, XCD-grouped mapping inside kernel
    hyp_dist_tile_kernel<<<dim3(32 * 16 * 16), dim3(256), 0, stream>>>(q, k, out);
}